// Round 8
// baseline (81.238 us; speedup 1.0000x reference)
//
#include <hip/hip_runtime.h>
#include <math.h>

// PartialAttention: LN -> Q/K proj -> scaled QK^T -> rowmax-subtracted exp.
// S=4096, B=2, E=1024, D=64. Out [B,S,S] f32 = 134 MB.
//
// Kernel A (lnsplit_wprep): 2048 blocks x 256 thr, one 4-row quarter-tile
//   per block, barrier-free: each wave loads its row's 32 elems to regs,
//   shfl-reduces LN stats, normalizes + RNE hi/lo splits from registers,
//   writes frag-ordered 16B stores to xh/xl (L3). Blocks >= 2048 run the
//   proven wprep body (W -> bf16 hi/lo B-frags).
// Kernel B (proj): r6 verbatim (proven): split-K=4, 32 rows/block, 8 waves,
//   A-frags LDS-staged, 4-term hi/lo MFMA, f32 partial-C frags.
// Kernel R (reduce): r6 verbatim (proven): sum 4 partials + bias -> qk tile
//   -> proven phase-3 splitter -> q/k frag arrays.
// Kernel S (score): verbatim r2/r5 (write-roofline).

typedef __attribute__((ext_vector_type(4))) float f32x4;
typedef __attribute__((ext_vector_type(8))) short bf16x8;
typedef __attribute__((ext_vector_type(8))) unsigned short u16x8;

#define SLEN 4096
#define BATCH 2
#define EDIM 1024
#define DDIM 64
#define QK_STRIDE 136    // q cols [0,64), k cols [68,132)

__device__ __forceinline__ unsigned short f2bf(float f) {
    unsigned int u = __float_as_uint(f);
    u += 0x7FFFu + ((u >> 16) & 1u);   // RNE to bf16
    return (unsigned short)(u >> 16);
}
__device__ __forceinline__ float bf2f(unsigned short h) {
    return __uint_as_float(((unsigned int)h) << 16);
}

// ---------------- kernel A: LN+split (barrier-free) + wprep ----------------
// A-frag: xh/xl slot = (gt*32 + kg)*64 + lane;
//   value j = xnorm[row = lane&15 of tile gt][kg*32 + ((lane>>4)&3)*8 + j]
// W-frag: slot = (ct*32 + kg)*64 + l;
//   value j = W[kg*32 + ((l>>4)&3)*8 + j][ct*16 + (l&15)]
__global__ __launch_bounds__(256, 4) void lnsplit_wprep_kernel(
    const float* __restrict__ src, const float* __restrict__ gamma,
    const float* __restrict__ beta,
    const float* __restrict__ Wq, const float* __restrict__ Wk,
    unsigned short* __restrict__ xh, unsigned short* __restrict__ xl,
    unsigned short* __restrict__ whf, unsigned short* __restrict__ wlf)
{
    const int bid = blockIdx.x;
    const int tid = threadIdx.x;

    if (bid >= 2048) {   // ---- wprep role (verbatim r5/r6 body) ----
        const int slot = (bid - 2048) * 256 + tid;   // 0..16383
        const int ct = slot >> 11;
        const int kg = (slot >> 6) & 31;
        const int l  = slot & 63;
        const int c  = ct * 16 + (l & 15);
        const int kb = kg * 32 + ((l >> 4) & 3) * 8;
        const float* Wm = (c < DDIM) ? (Wq + c) : (Wk + (c - DDIM));
        u16x8 hv, lv;
#pragma unroll
        for (int j = 0; j < 8; ++j) {
            const float v = Wm[(size_t)(kb + j) * DDIM];
            const unsigned short h = f2bf(v);
            hv[j] = h;
            lv[j] = f2bf(v - bf2f(h));
        }
        *reinterpret_cast<u16x8*>(whf + (size_t)slot * 8) = hv;
        *reinterpret_cast<u16x8*>(wlf + (size_t)slot * 8) = lv;
        return;
    }

    // ---- LN + split role: block = (gt, quarter); wave w owns one row ----
    const int gt = bid >> 2;               // 0..511
    const int q  = bid & 3;
    const int w  = tid >> 6;               // wave 0..3
    const int l  = tid & 63;
    const int b  = gt >> 8;
    const int s  = (gt & 255) * 16 + q * 4 + w;   // global seq index
    const float* row = src + ((size_t)s * BATCH + b) * EDIM;
    const int e0 = 8 * l;                  // lane's elems: [e0,e0+8) and [512+e0,512+e0+8)

    const float4 v0 = *reinterpret_cast<const float4*>(row + e0);
    const float4 v1 = *reinterpret_cast<const float4*>(row + e0 + 4);
    const float4 v2 = *reinterpret_cast<const float4*>(row + 512 + e0);
    const float4 v3 = *reinterpret_cast<const float4*>(row + 512 + e0 + 4);

    float sum = v0.x + v0.y + v0.z + v0.w + v1.x + v1.y + v1.z + v1.w
              + v2.x + v2.y + v2.z + v2.w + v3.x + v3.y + v3.z + v3.w;
    float sq  = v0.x*v0.x + v0.y*v0.y + v0.z*v0.z + v0.w*v0.w
              + v1.x*v1.x + v1.y*v1.y + v1.z*v1.z + v1.w*v1.w
              + v2.x*v2.x + v2.y*v2.y + v2.z*v2.z + v2.w*v2.w
              + v3.x*v3.x + v3.y*v3.y + v3.z*v3.z + v3.w*v3.w;
#pragma unroll
    for (int off = 1; off < 64; off <<= 1) {
        sum += __shfl_xor(sum, off);
        sq  += __shfl_xor(sq,  off);
    }
    const float mu   = sum * (1.f / EDIM);
    const float rstd = rsqrtf(sq * (1.f / EDIM) - mu * mu + 1e-5f);

    const float4 g0 = *reinterpret_cast<const float4*>(gamma + e0);
    const float4 g1 = *reinterpret_cast<const float4*>(gamma + e0 + 4);
    const float4 g2 = *reinterpret_cast<const float4*>(gamma + 512 + e0);
    const float4 g3 = *reinterpret_cast<const float4*>(gamma + 512 + e0 + 4);
    const float4 t0 = *reinterpret_cast<const float4*>(beta + e0);
    const float4 t1 = *reinterpret_cast<const float4*>(beta + e0 + 4);
    const float4 t2 = *reinterpret_cast<const float4*>(beta + 512 + e0);
    const float4 t3 = *reinterpret_cast<const float4*>(beta + 512 + e0 + 4);

    const float va[8] = {
        (v0.x - mu) * rstd * g0.x + t0.x, (v0.y - mu) * rstd * g0.y + t0.y,
        (v0.z - mu) * rstd * g0.z + t0.z, (v0.w - mu) * rstd * g0.w + t0.w,
        (v1.x - mu) * rstd * g1.x + t1.x, (v1.y - mu) * rstd * g1.y + t1.y,
        (v1.z - mu) * rstd * g1.z + t1.z, (v1.w - mu) * rstd * g1.w + t1.w };
    const float vb[8] = {
        (v2.x - mu) * rstd * g2.x + t2.x, (v2.y - mu) * rstd * g2.y + t2.y,
        (v2.z - mu) * rstd * g2.z + t2.z, (v2.w - mu) * rstd * g2.w + t2.w,
        (v3.x - mu) * rstd * g3.x + t3.x, (v3.y - mu) * rstd * g3.y + t3.y,
        (v3.z - mu) * rstd * g3.z + t3.z, (v3.w - mu) * rstd * g3.w + t3.w };

    u16x8 ha, la, hb, lb;
#pragma unroll
    for (int j = 0; j < 8; ++j) {
        unsigned short h = f2bf(va[j]);
        ha[j] = h; la[j] = f2bf(va[j] - bf2f(h));
        h = f2bf(vb[j]);
        hb[j] = h; lb[j] = f2bf(vb[j] - bf2f(h));
    }

    // group g0 = l: kg = l>>2, p = l&3, elems row[8l..8l+8)   (kg*32+p*8 == 8l)
    // group g1 = l+64: kg = 16 + (l>>2), elems row[512+8l ..)
    const int kg0  = l >> 2;
    const int p    = l & 3;
    const int lane = (q * 4 + w) | (p << 4);
    const size_t slot0 = ((size_t)gt * 32 + kg0) * 64 + lane;
    const size_t slot1 = ((size_t)gt * 32 + kg0 + 16) * 64 + lane;
    *reinterpret_cast<u16x8*>(xh + slot0 * 8) = ha;
    *reinterpret_cast<u16x8*>(xl + slot0 * 8) = la;
    *reinterpret_cast<u16x8*>(xh + slot1 * 8) = hb;
    *reinterpret_cast<u16x8*>(xl + slot1 * 8) = lb;
}

// ---------------- kernel B: MFMA projection, split-K=4 (verbatim r6) ----------------
__global__ __launch_bounds__(512, 4) void proj_kernel(
    const unsigned short* __restrict__ xh, const unsigned short* __restrict__ xl,
    const unsigned short* __restrict__ whf, const unsigned short* __restrict__ wlf,
    float* __restrict__ pc)
{
    __shared__ u16x8 sa[2][2][8][64];      // [hl][t2][kg][lane], 32 KB
    const int tid  = threadIdx.x;
    const int lane = tid & 63;
    const int ct   = tid >> 6;             // wave = col-tile 0..7
    const int bid  = blockIdx.x;           // 0..1023
    const int mg   = bid >> 2;             // 0..255
    const int ksl  = bid & 3;
    const int gt0  = mg * 2;

    u16x8* sl = &sa[0][0][0][0];
#pragma unroll
    for (int p = 0; p < 4; ++p) {
        const int sidx = p * 512 + tid;
        const int hl   = sidx >> 10;
        const int rem  = sidx & 1023;
        const int t2   = rem >> 9;
        const int kg   = (rem >> 6) & 7;
        const int ln   = rem & 63;
        const size_t gslot = (((size_t)(gt0 + t2)) * 32 + ksl * 8 + kg) * 64 + ln;
        const unsigned short* srcp = hl ? xl : xh;
        sl[sidx] = *reinterpret_cast<const u16x8*>(srcp + gslot * 8);
    }
    __syncthreads();

    f32x4 acc0 = {0.f, 0.f, 0.f, 0.f};
    f32x4 acc1 = {0.f, 0.f, 0.f, 0.f};
#pragma unroll
    for (int kg = 0; kg < 8; ++kg) {
        const bf16x8 ah0 = *reinterpret_cast<const bf16x8*>(&sa[0][0][kg][lane]);
        const bf16x8 al0 = *reinterpret_cast<const bf16x8*>(&sa[1][0][kg][lane]);
        const bf16x8 ah1 = *reinterpret_cast<const bf16x8*>(&sa[0][1][kg][lane]);
        const bf16x8 al1 = *reinterpret_cast<const bf16x8*>(&sa[1][1][kg][lane]);
        const size_t wslot = ((size_t)ct * 32 + ksl * 8 + kg) * 64 + lane;
        const bf16x8 bh = *reinterpret_cast<const bf16x8*>(whf + wslot * 8);
        const bf16x8 bl = *reinterpret_cast<const bf16x8*>(wlf + wslot * 8);
        acc0 = __builtin_amdgcn_mfma_f32_16x16x32_bf16(ah0, bh, acc0, 0, 0, 0);
        acc1 = __builtin_amdgcn_mfma_f32_16x16x32_bf16(ah1, bh, acc1, 0, 0, 0);
        acc0 = __builtin_amdgcn_mfma_f32_16x16x32_bf16(al0, bh, acc0, 0, 0, 0);
        acc1 = __builtin_amdgcn_mfma_f32_16x16x32_bf16(al1, bh, acc1, 0, 0, 0);
        acc0 = __builtin_amdgcn_mfma_f32_16x16x32_bf16(ah0, bl, acc0, 0, 0, 0);
        acc1 = __builtin_amdgcn_mfma_f32_16x16x32_bf16(ah1, bl, acc1, 0, 0, 0);
        acc0 = __builtin_amdgcn_mfma_f32_16x16x32_bf16(al0, bl, acc0, 0, 0, 0);
        acc1 = __builtin_amdgcn_mfma_f32_16x16x32_bf16(al1, bl, acc1, 0, 0, 0);
    }
    {
        const size_t p0 = ((((size_t)gt0 * 4) + ksl) * 8 + ct) * 64 + lane;
        const size_t p1 = ((((size_t)(gt0 + 1) * 4) + ksl) * 8 + ct) * 64 + lane;
        float4 o0 = {acc0[0], acc0[1], acc0[2], acc0[3]};
        float4 o1 = {acc1[0], acc1[1], acc1[2], acc1[3]};
        *reinterpret_cast<float4*>(pc + p0 * 4) = o0;
        *reinterpret_cast<float4*>(pc + p1 * 4) = o1;
    }
}

// ---------------- kernel R: reduce partials + bias + split (verbatim r6) ----------------
__global__ __launch_bounds__(256, 2) void reduce_kernel(
    const float* __restrict__ pc,
    const float* __restrict__ bq, const float* __restrict__ bk,
    unsigned short* __restrict__ qhf, unsigned short* __restrict__ qlf,
    unsigned short* __restrict__ khf, unsigned short* __restrict__ klf)
{
    __shared__ float qk[16 * QK_STRIDE];
    const int tid  = threadIdx.x;
    const int lane = tid & 63;
    const int wv   = tid >> 6;
    const int gt   = blockIdx.x;           // 0..511
    const int b    = gt >> 8;

#pragma unroll
    for (int cti = 0; cti < 2; ++cti) {
        const int ct = wv * 2 + cti;
        float4 s = {0.f, 0.f, 0.f, 0.f};
#pragma unroll
        for (int ksl = 0; ksl < 4; ++ksl) {
            const size_t p = ((((size_t)gt * 4) + ksl) * 8 + ct) * 64 + lane;
            const float4 v = *reinterpret_cast<const float4*>(pc + p * 4);
            s.x += v.x; s.y += v.y; s.z += v.z; s.w += v.w;
        }
        const int cj = ct * 16 + (lane & 15);
        const int r0 = (lane >> 4) * 4;
        const float bv = (cj < DDIM) ? bq[cj] : bk[cj - DDIM];
        const int cb = (cj < DDIM) ? cj : (68 + cj - DDIM);
        qk[(r0 + 0) * QK_STRIDE + cb] = s.x + bv;
        qk[(r0 + 1) * QK_STRIDE + cb] = s.y + bv;
        qk[(r0 + 2) * QK_STRIDE + cb] = s.z + bv;
        qk[(r0 + 3) * QK_STRIDE + cb] = s.w + bv;
    }
    __syncthreads();

    {
        const int l2  = tid & 63;
        const int dc  = (tid >> 6) & 1;
        const int isK = tid >> 7;
        const int row = l2 & 15;
        const int d0  = dc * 32 + ((l2 >> 4) & 3) * 8;
        const float* p = &qk[row * QK_STRIDE + (isK ? 68 : 0) + d0];
        const float sc = isK ? 1.0f : 0.125f;   // fold 1/sqrt(D) into q
        u16x8 hvv, lvv;
#pragma unroll
        for (int j = 0; j < 8; ++j) {
            const float vq = p[j] * sc;
            const unsigned short h = f2bf(vq);
            hvv[j] = h;
            lvv[j] = f2bf(vq - bf2f(h));
        }
        const size_t base = ((((size_t)b * 256 + (size_t)(gt & 255)) * 2 + dc) * 512) + (size_t)l2 * 8;
        *reinterpret_cast<u16x8*>((isK ? khf : qhf) + base) = hvv;
        *reinterpret_cast<u16x8*>((isK ? klf : qlf) + base) = lvv;
    }
}

// ---------------- kernel S: QK^T + rowmax + exp (verbatim r2/r5) ----------------
__global__ __launch_bounds__(1024, 1) void score_kernel(
    const unsigned short* __restrict__ qhf, const unsigned short* __restrict__ qlf,
    const unsigned short* __restrict__ khf, const unsigned short* __restrict__ klf,
    float* __restrict__ out)
{
    __shared__ float wmax[16 * 16];
    __shared__ float fmax_s[16];
    const int tid = threadIdx.x;
    const int l   = tid & 63;
    const int w   = tid >> 6;
    const int bid = blockIdx.x;
    const int b   = bid >> 8;
    const int rt  = bid & 255;

    const size_t abase = (((size_t)b * 256 + rt) * 2) * 512 + (size_t)l * 8;
    const bf16x8 qh0 = *reinterpret_cast<const bf16x8*>(qhf + abase);
    const bf16x8 qh1 = *reinterpret_cast<const bf16x8*>(qhf + abase + 512);
    const bf16x8 ql0 = *reinterpret_cast<const bf16x8*>(qlf + abase);
    const bf16x8 ql1 = *reinterpret_cast<const bf16x8*>(qlf + abase + 512);

    f32x4 acc[16];
#pragma unroll
    for (int i = 0; i < 16; ++i) acc[i] = (f32x4){0.f, 0.f, 0.f, 0.f};

#pragma unroll
    for (int i = 0; i < 16; ++i) {
        const int ct = w * 16 + i;
        const size_t kb = (((size_t)b * 256 + ct) * 2) * 512 + (size_t)l * 8;
        const bf16x8 kh0 = *reinterpret_cast<const bf16x8*>(khf + kb);
        const bf16x8 kh1 = *reinterpret_cast<const bf16x8*>(khf + kb + 512);
        const bf16x8 kl0 = *reinterpret_cast<const bf16x8*>(klf + kb);
        const bf16x8 kl1 = *reinterpret_cast<const bf16x8*>(klf + kb + 512);
        f32x4 a = acc[i];
        a = __builtin_amdgcn_mfma_f32_16x16x32_bf16(qh0, kh0, a, 0, 0, 0);
        a = __builtin_amdgcn_mfma_f32_16x16x32_bf16(qh1, kh1, a, 0, 0, 0);
        a = __builtin_amdgcn_mfma_f32_16x16x32_bf16(qh0, kl0, a, 0, 0, 0);
        a = __builtin_amdgcn_mfma_f32_16x16x32_bf16(qh1, kl1, a, 0, 0, 0);
        a = __builtin_amdgcn_mfma_f32_16x16x32_bf16(ql0, kh0, a, 0, 0, 0);
        a = __builtin_amdgcn_mfma_f32_16x16x32_bf16(ql1, kh1, a, 0, 0, 0);
        acc[i] = a;
    }

    float m4[4];
#pragma unroll
    for (int r = 0; r < 4; ++r) {
        m4[r] = acc[0][r];
#pragma unroll
        for (int i = 1; i < 16; ++i) m4[r] = fmaxf(m4[r], acc[i][r]);
    }
#pragma unroll
    for (int off = 1; off < 16; off <<= 1) {
#pragma unroll
        for (int r = 0; r < 4; ++r) m4[r] = fmaxf(m4[r], __shfl_xor(m4[r], off));
    }
    const int rgrp = l >> 4;
    if ((l & 15) == 0) {
#pragma unroll
        for (int r = 0; r < 4; ++r) wmax[w * 16 + rgrp * 4 + r] = m4[r];
    }
    __syncthreads();
    if (tid < 16) {
        float m = wmax[tid];
#pragma unroll
        for (int ww = 1; ww < 16; ++ww) m = fmaxf(m, wmax[ww * 16 + tid]);
        fmax_s[tid] = m;
    }
    __syncthreads();

    float fm[4];
#pragma unroll
    for (int r = 0; r < 4; ++r) fm[r] = fmax_s[rgrp * 4 + r];
    const int cres = l & 15;
    const size_t obase = ((size_t)b * SLEN + (size_t)rt * 16) * SLEN;
#pragma unroll
    for (int i = 0; i < 16; ++i) {
        const int col = (w * 16 + i) * 16 + cres;
#pragma unroll
        for (int r = 0; r < 4; ++r)
            out[obase + (size_t)(rgrp * 4 + r) * SLEN + col] = __expf(acc[i][r] - fm[r]);
    }
}

extern "C" void kernel_launch(void* const* d_in, const int* in_sizes, int n_in,
                              void* d_out, int out_size, void* d_ws, size_t ws_size,
                              hipStream_t stream) {
    (void)in_sizes; (void)n_in;
    const float* src   = (const float*)d_in[0];
    const float* gamma = (const float*)d_in[1];
    const float* beta  = (const float*)d_in[2];
    const float* Wq    = (const float*)d_in[3];
    const float* bq    = (const float*)d_in[4];
    const float* Wk    = (const float*)d_in[5];
    const float* bk    = (const float*)d_in[6];
    float* out = (float*)d_out;

    unsigned short* ws  = (unsigned short*)d_ws;
    unsigned short* qhf = ws;
    unsigned short* qlf = ws + (1u << 19);
    unsigned short* khf = ws + (2u << 19);
    unsigned short* klf = ws + (3u << 19);

    // big scratch: whf/wlf (256 KB ea) + xh/xl (16 MB ea) + pc (16 MB)
    const size_t WF = 131072;        // shorts per W frag array
    const size_t XF = 8388608;       // shorts per x frag array (16 MB)
    const size_t big_bytes = 2 * WF * 2 + 2 * XF * 2 + (size_t)4194304 * 4;
    const size_t need = (4u << 20) + big_bytes;
    unsigned short *whf, *wlf, *xh, *xl;
    float* pc;
    if (ws_size >= need) {
        whf = ws + (4u << 19);
        wlf = whf + WF;
        xh  = wlf + WF;
        xl  = xh + XF;
        pc  = (float*)(xl + XF);
    } else {
        const size_t out_bytes = (size_t)out_size * 4;
        size_t base = (out_bytes - big_bytes) & ~(size_t)255;
        char* tp = (char*)d_out + base;
        whf = (unsigned short*)tp;            tp += WF * 2;
        wlf = (unsigned short*)tp;            tp += WF * 2;
        xh  = (unsigned short*)tp;            tp += XF * 2;
        xl  = (unsigned short*)tp;            tp += XF * 2;
        pc  = (float*)tp;
    }

    hipLaunchKernelGGL(lnsplit_wprep_kernel, dim3(2112), dim3(256), 0, stream,
                       src, gamma, beta, Wq, Wk, xh, xl, whf, wlf);
    hipLaunchKernelGGL(proj_kernel, dim3(1024), dim3(512), 0, stream,
                       xh, xl, whf, wlf, pc);
    hipLaunchKernelGGL(reduce_kernel, dim3(512), dim3(256), 0, stream,
                       pc, bq, bk, qhf, qlf, khf, klf);
    hipLaunchKernelGGL(score_kernel, dim3(512), dim3(1024), 0, stream,
                       qhf, qlf, khf, klf, out);
}

// Round 10
// 72.478 us; speedup vs baseline: 1.1209x; 1.1209x over previous
//
#include <hip/hip_runtime.h>
#include <math.h>

// PartialAttention: LN -> Q/K proj -> scaled QK^T -> rowmax-subtracted exp.
// S=4096, B=2, E=1024, D=64. Out [B,S,S] f32 = 134 MB.
//
// Base = round-7 kernel (PASSED, 73.4 us) with ONE change: T14 async-STAGE
// split in ln_proj — STAGE_LOAD issues next chunk's 6 float4 loads before
// the MFMA loop, STAGE_FIN (wait+convert+LDS write) runs after it. Data
// path byte-identical to r7; only load scheduling changes.
//
// Kernel W (wprep): W -> bf16 RNE hi/lo B-frag arrays (verbatim r5, proven).
// Kernel 1 (ln_proj): fused, 512 thr (8 waves), 16 rows/block, dbuf LDS
//   A-frags, 4-term hi/lo MFMA, proven epilogue + splitter.
// Kernel S (score): verbatim r2/r5 (write-roofline).

typedef __attribute__((ext_vector_type(4))) float f32x4;
typedef __attribute__((ext_vector_type(8))) short bf16x8;
typedef __attribute__((ext_vector_type(8))) unsigned short u16x8;

#define SLEN 4096
#define BATCH 2
#define EDIM 1024
#define DDIM 64
#define QK_STRIDE 136    // q cols [0,64), k cols [68,132)

__device__ __forceinline__ unsigned short f2bf(float f) {
    unsigned int u = __float_as_uint(f);
    u += 0x7FFFu + ((u >> 16) & 1u);   // RNE to bf16
    return (unsigned short)(u >> 16);
}
__device__ __forceinline__ float bf2f(unsigned short h) {
    return __uint_as_float(((unsigned int)h) << 16);
}

// ---------------- kernel W: W fragment prep (verbatim r5, proven) ----------------
// slot = (ct*32 + kg)*64 + l; value j = W[kg*32 + ((l>>4)&3)*8 + j][ct*16 + (l&15)]
__global__ __launch_bounds__(256) void wprep_kernel(
    const float* __restrict__ Wq, const float* __restrict__ Wk,
    unsigned short* __restrict__ whf, unsigned short* __restrict__ wlf)
{
    const int slot = blockIdx.x * 256 + threadIdx.x;   // 0..16383
    const int ct = slot >> 11;
    const int kg = (slot >> 6) & 31;
    const int l  = slot & 63;
    const int c  = ct * 16 + (l & 15);
    const int kb = kg * 32 + ((l >> 4) & 3) * 8;
    const float* Wm = (c < DDIM) ? (Wq + c) : (Wk + (c - DDIM));
    u16x8 hv, lv;
#pragma unroll
    for (int j = 0; j < 8; ++j) {
        const float v = Wm[(size_t)(kb + j) * DDIM];
        const unsigned short h = f2bf(v);
        hv[j] = h;
        lv[j] = f2bf(v - bf2f(h));
    }
    *reinterpret_cast<u16x8*>(whf + (size_t)slot * 8) = hv;
    *reinterpret_cast<u16x8*>(wlf + (size_t)slot * 8) = lv;
}

// ---------------- kernel 1: LN + MFMA projection (r7 + async-STAGE split) ----------------
__global__ __launch_bounds__(512, 2) void ln_proj_kernel(
    const float* __restrict__ src, const float* __restrict__ gamma,
    const float* __restrict__ beta,
    const float* __restrict__ bq, const float* __restrict__ bk,
    const unsigned short* __restrict__ whf, const unsigned short* __restrict__ wlf,
    unsigned short* __restrict__ qhf, unsigned short* __restrict__ qlf,
    unsigned short* __restrict__ khf, unsigned short* __restrict__ klf)
{
    __shared__ u16x8 xhf[2][8][64];        // 16 KB: A-frag hi, dbuf per chunk
    __shared__ u16x8 xlf[2][8][64];        // 16 KB: A-frag lo
    __shared__ float2 stats[16];
    __shared__ float qk[16 * QK_STRIDE];   // 8.7 KB
    const int tid  = threadIdx.x;
    const int lane = tid & 63;
    const int wv   = tid >> 6;             // 0..7
    const int gt   = blockIdx.x;           // 0..511
    const int b    = gt >> 8;
    const int s0   = (gt & 255) * 16;

    // ---- phase A: LN stats, 2 rows per wave (verbatim r7) ----
    for (int ii = 0; ii < 2; ++ii) {
        const int i = wv * 2 + ii;
        const float* row = src + ((size_t)(s0 + i) * BATCH + b) * EDIM;
        float sum = 0.f, sq = 0.f;
#pragma unroll
        for (int k = 0; k < 4; ++k) {
            float4 v = *reinterpret_cast<const float4*>(row + k * 256 + lane * 4);
            sum += v.x + v.y + v.z + v.w;
            sq  += v.x*v.x + v.y*v.y + v.z*v.z + v.w*v.w;
        }
#pragma unroll
        for (int off = 1; off < 64; off <<= 1) {
            sum += __shfl_xor(sum, off);
            sq  += __shfl_xor(sq,  off);
        }
        if (lane == 0) {
            const float mu   = sum * (1.f / EDIM);
            const float rstd = rsqrtf(sq * (1.f / EDIM) - mu * mu + 1e-5f);
            stats[i] = make_float2(mu, rstd);
        }
    }
    __syncthreads();

    // staging role (verbatim r7 mapping): frag slot (kg = wv, lane); reads 8
    // floats of row (lane&15) at col c*256 + wv*32 + (lane>>4)*8.
    const int srow = lane & 15;
    const int scol = wv * 32 + (lane >> 4) * 8;
    const float* srcrow = src + ((size_t)(s0 + srow) * BATCH + b) * EDIM;
    const float smu = stats[srow].x;
    const float srs = stats[srow].y;

    float4 Lva, Lvb, Lga, Lgb, Lba, Lbb;   // pipelined chunk registers

#define STAGE_LOAD(c)                                                         \
    {                                                                         \
        const int cb_ = (c) * 256 + scol;                                     \
        Lva = *reinterpret_cast<const float4*>(srcrow + cb_);                 \
        Lvb = *reinterpret_cast<const float4*>(srcrow + cb_ + 4);             \
        Lga = *reinterpret_cast<const float4*>(gamma + cb_);                  \
        Lgb = *reinterpret_cast<const float4*>(gamma + cb_ + 4);              \
        Lba = *reinterpret_cast<const float4*>(beta + cb_);                   \
        Lbb = *reinterpret_cast<const float4*>(beta + cb_ + 4);               \
    }

#define STAGE_FIN(bf)                                                         \
    {                                                                         \
        const float vv[8] = {                                                 \
            (Lva.x - smu) * srs * Lga.x + Lba.x,                              \
            (Lva.y - smu) * srs * Lga.y + Lba.y,                              \
            (Lva.z - smu) * srs * Lga.z + Lba.z,                              \
            (Lva.w - smu) * srs * Lga.w + Lba.w,                              \
            (Lvb.x - smu) * srs * Lgb.x + Lbb.x,                              \
            (Lvb.y - smu) * srs * Lgb.y + Lbb.y,                              \
            (Lvb.z - smu) * srs * Lgb.z + Lbb.z,                              \
            (Lvb.w - smu) * srs * Lgb.w + Lbb.w };                            \
        u16x8 hv, lv;                                                         \
        _Pragma("unroll")                                                     \
        for (int j = 0; j < 8; ++j) {                                         \
            const unsigned short h = f2bf(vv[j]);                             \
            hv[j] = h;                                                        \
            lv[j] = f2bf(vv[j] - bf2f(h));                                    \
        }                                                                     \
        xhf[bf][wv][lane] = hv;                                               \
        xlf[bf][wv][lane] = lv;                                               \
    }

    // compute role: wave wv owns col-tile ct = wv (verbatim r7)
    f32x4 acc = {0.f, 0.f, 0.f, 0.f};

    STAGE_LOAD(0);
    STAGE_FIN(0);
    __syncthreads();

    for (int c = 0; c < 4; ++c) {
        const int cur = c & 1;
        if (c < 3) STAGE_LOAD(c + 1);      // issue loads; hide under MFMAs
#pragma unroll
        for (int kg = 0; kg < 8; ++kg) {
            const bf16x8 ah = *reinterpret_cast<const bf16x8*>(&xhf[cur][kg][lane]);
            const bf16x8 al = *reinterpret_cast<const bf16x8*>(&xlf[cur][kg][lane]);
            const size_t wslot = ((size_t)wv * 32 + c * 8 + kg) * 64 + lane;
            const bf16x8 bh = *reinterpret_cast<const bf16x8*>(whf + wslot * 8);
            const bf16x8 bl = *reinterpret_cast<const bf16x8*>(wlf + wslot * 8);
            acc = __builtin_amdgcn_mfma_f32_16x16x32_bf16(ah, bh, acc, 0, 0, 0);
            acc = __builtin_amdgcn_mfma_f32_16x16x32_bf16(al, bh, acc, 0, 0, 0);
            acc = __builtin_amdgcn_mfma_f32_16x16x32_bf16(ah, bl, acc, 0, 0, 0);
            acc = __builtin_amdgcn_mfma_f32_16x16x32_bf16(al, bl, acc, 0, 0, 0);
        }
        if (c < 3) STAGE_FIN(cur ^ 1);     // wait+convert+write after MFMAs
        __syncthreads();
    }
#undef STAGE_LOAD
#undef STAGE_FIN

    // ---- epilogue (verbatim r7): bias, f32 qk tile ----
    {
        const int cj = wv * 16 + (lane & 15);
        const int r0 = (lane >> 4) * 4;
        const float bv = (cj < DDIM) ? bq[cj] : bk[cj - DDIM];
        const int cb = (cj < DDIM) ? cj : (68 + cj - DDIM);
#pragma unroll
        for (int r = 0; r < 4; ++r)
            qk[(r0 + r) * QK_STRIDE + cb] = acc[r] + bv;
    }
    __syncthreads();

    // ---- phase 3 (verbatim r2/r5/r7, proven): RNE hi/lo split to frag order ----
    if (tid < 256) {
        const int l2  = tid & 63;
        const int dc  = (tid >> 6) & 1;
        const int isK = tid >> 7;
        const int row = l2 & 15;
        const int d0  = dc * 32 + ((l2 >> 4) & 3) * 8;
        const float* p = &qk[row * QK_STRIDE + (isK ? 68 : 0) + d0];
        const float sc = isK ? 1.0f : 0.125f;   // fold 1/sqrt(D) into q
        u16x8 hvv, lvv;
#pragma unroll
        for (int j = 0; j < 8; ++j) {
            const float vq = p[j] * sc;
            const unsigned short h = f2bf(vq);
            hvv[j] = h;
            lvv[j] = f2bf(vq - bf2f(h));
        }
        const size_t base = ((((size_t)b * 256 + (size_t)(gt & 255)) * 2 + dc) * 512) + (size_t)l2 * 8;
        *reinterpret_cast<u16x8*>((isK ? khf : qhf) + base) = hvv;
        *reinterpret_cast<u16x8*>((isK ? klf : qlf) + base) = lvv;
    }
}

// ---------------- kernel S: QK^T + rowmax + exp (verbatim r2/r5) ----------------
__global__ __launch_bounds__(1024, 1) void score_kernel(
    const unsigned short* __restrict__ qhf, const unsigned short* __restrict__ qlf,
    const unsigned short* __restrict__ khf, const unsigned short* __restrict__ klf,
    float* __restrict__ out)
{
    __shared__ float wmax[16 * 16];
    __shared__ float fmax_s[16];
    const int tid = threadIdx.x;
    const int l   = tid & 63;
    const int w   = tid >> 6;
    const int bid = blockIdx.x;
    const int b   = bid >> 8;
    const int rt  = bid & 255;

    const size_t abase = (((size_t)b * 256 + rt) * 2) * 512 + (size_t)l * 8;
    const bf16x8 qh0 = *reinterpret_cast<const bf16x8*>(qhf + abase);
    const bf16x8 qh1 = *reinterpret_cast<const bf16x8*>(qhf + abase + 512);
    const bf16x8 ql0 = *reinterpret_cast<const bf16x8*>(qlf + abase);
    const bf16x8 ql1 = *reinterpret_cast<const bf16x8*>(qlf + abase + 512);

    f32x4 acc[16];
#pragma unroll
    for (int i = 0; i < 16; ++i) acc[i] = (f32x4){0.f, 0.f, 0.f, 0.f};

#pragma unroll
    for (int i = 0; i < 16; ++i) {
        const int ct = w * 16 + i;
        const size_t kb = (((size_t)b * 256 + ct) * 2) * 512 + (size_t)l * 8;
        const bf16x8 kh0 = *reinterpret_cast<const bf16x8*>(khf + kb);
        const bf16x8 kh1 = *reinterpret_cast<const bf16x8*>(khf + kb + 512);
        const bf16x8 kl0 = *reinterpret_cast<const bf16x8*>(klf + kb);
        const bf16x8 kl1 = *reinterpret_cast<const bf16x8*>(klf + kb + 512);
        f32x4 a = acc[i];
        a = __builtin_amdgcn_mfma_f32_16x16x32_bf16(qh0, kh0, a, 0, 0, 0);
        a = __builtin_amdgcn_mfma_f32_16x16x32_bf16(qh1, kh1, a, 0, 0, 0);
        a = __builtin_amdgcn_mfma_f32_16x16x32_bf16(qh0, kl0, a, 0, 0, 0);
        a = __builtin_amdgcn_mfma_f32_16x16x32_bf16(qh1, kl1, a, 0, 0, 0);
        a = __builtin_amdgcn_mfma_f32_16x16x32_bf16(ql0, kh0, a, 0, 0, 0);
        a = __builtin_amdgcn_mfma_f32_16x16x32_bf16(ql1, kh1, a, 0, 0, 0);
        acc[i] = a;
    }

    float m4[4];
#pragma unroll
    for (int r = 0; r < 4; ++r) {
        m4[r] = acc[0][r];
#pragma unroll
        for (int i = 1; i < 16; ++i) m4[r] = fmaxf(m4[r], acc[i][r]);
    }
#pragma unroll
    for (int off = 1; off < 16; off <<= 1) {
#pragma unroll
        for (int r = 0; r < 4; ++r) m4[r] = fmaxf(m4[r], __shfl_xor(m4[r], off));
    }
    const int rgrp = l >> 4;
    if ((l & 15) == 0) {
#pragma unroll
        for (int r = 0; r < 4; ++r) wmax[w * 16 + rgrp * 4 + r] = m4[r];
    }
    __syncthreads();
    if (tid < 16) {
        float m = wmax[tid];
#pragma unroll
        for (int ww = 1; ww < 16; ++ww) m = fmaxf(m, wmax[ww * 16 + tid]);
        fmax_s[tid] = m;
    }
    __syncthreads();

    float fm[4];
#pragma unroll
    for (int r = 0; r < 4; ++r) fm[r] = fmax_s[rgrp * 4 + r];
    const int cres = l & 15;
    const size_t obase = ((size_t)b * SLEN + (size_t)rt * 16) * SLEN;
#pragma unroll
    for (int i = 0; i < 16; ++i) {
        const int col = (w * 16 + i) * 16 + cres;
#pragma unroll
        for (int r = 0; r < 4; ++r)
            out[obase + (size_t)(rgrp * 4 + r) * SLEN + col] = __expf(acc[i][r] - fm[r]);
    }
}

extern "C" void kernel_launch(void* const* d_in, const int* in_sizes, int n_in,
                              void* d_out, int out_size, void* d_ws, size_t ws_size,
                              hipStream_t stream) {
    (void)in_sizes; (void)n_in;
    const float* src   = (const float*)d_in[0];
    const float* gamma = (const float*)d_in[1];
    const float* beta  = (const float*)d_in[2];
    const float* Wq    = (const float*)d_in[3];
    const float* bq    = (const float*)d_in[4];
    const float* Wk    = (const float*)d_in[5];
    const float* bk    = (const float*)d_in[6];
    float* out = (float*)d_out;

    // ws: qhf/qlf/khf/klf 1 MB each; then whf/wlf 256 KB each (r5 scheme).
    unsigned short* ws  = (unsigned short*)d_ws;
    unsigned short* qhf = ws;
    unsigned short* qlf = ws + (1u << 19);
    unsigned short* khf = ws + (2u << 19);
    unsigned short* klf = ws + (3u << 19);

    const size_t wfrag_shorts = 131072;             // 256 KB each
    const size_t need_bytes = (4u << 20) + 2 * 256 * 1024;
    unsigned short *whf, *wlf;
    if (ws_size >= need_bytes) {
        whf = ws + (4u << 19);
        wlf = whf + wfrag_shorts;
    } else {
        // park W frags in d_out tail: wprep writes -> ln_proj reads ->
        // score overwrites every byte afterwards (stream-ordered).
        const size_t out_bytes = (size_t)out_size * 4;
        char* tail = (char*)d_out + (out_bytes - (2 * 256 * 1024 + 4096));
        whf = (unsigned short*)tail;
        wlf = whf + wfrag_shorts;
    }

    hipLaunchKernelGGL(wprep_kernel, dim3(64), dim3(256), 0, stream,
                       Wq, Wk, whf, wlf);
    hipLaunchKernelGGL(ln_proj_kernel, dim3(512), dim3(512), 0, stream,
                       src, gamma, beta, bq, bk, whf, wlf, qhf, qlf, khf, klf);
    hipLaunchKernelGGL(score_kernel, dim3(512), dim3(1024), 0, stream,
                       qhf, qlf, khf, klf, out);
}